// Round 1
// 769.309 us; speedup vs baseline: 1.4220x; 1.4220x over previous
//
#include <hip/hip_runtime.h>

#define NB   8192
#define BATCH 2
#define FIN  128
#define FO   64
#define SPLIT 4
#define NSUP (NB / SPLIT / 64)                  // 32 super-tiles of 64 kv

typedef _Float16 f16;
typedef _Float16 f16x4 __attribute__((ext_vector_type(4)));
typedef _Float16 f16x8 __attribute__((ext_vector_type(8)));
typedef float    f32x4 __attribute__((ext_vector_type(4)));

__device__ __forceinline__ f32x4 mfma16(f16x4 a, f16x4 b, f32x4 c) {
    return __builtin_amdgcn_mfma_f32_16x16x16f16(a, b, c, 0, 0, 0);
}
__device__ __forceinline__ f32x4 mfma32(f16x8 a, f16x8 b, f32x4 c) {
    return __builtin_amdgcn_mfma_f32_16x16x32_f16(a, b, c, 0, 0, 0);
}

#define GLOAD_LDS16(gsrc, ldst)                                                   \
    __builtin_amdgcn_global_load_lds(                                             \
        (const __attribute__((address_space(1))) unsigned int*)(gsrc),            \
        (__attribute__((address_space(3))) unsigned int*)(ldst), 16, 0, 0)

// ---------------- kernel 0: weight prep (fp32 -> fp16, transposed) ----------
__global__ void k_prep(const float* __restrict__ W11, const float* __restrict__ W21,
                       const float* __restrict__ W31, const float* __restrict__ W12,
                       const float* __restrict__ W22, const float* __restrict__ W32,
                       f16* __restrict__ W1t, f16* __restrict__ W2t) {
    int gid = blockIdx.x * 256 + threadIdx.x;
    if (gid < 3 * FIN * FO) {                    // 24576: W1t[m][c][k] = W1[m][k][c]
        int m = gid >> 13, rem = gid & (FIN * FO - 1);
        int k = rem >> 6, c = rem & 63;
        const float* src = m == 0 ? W11 : (m == 1 ? W21 : W31);
        W1t[m * FIN * FO + c * FIN + k] = (f16)src[k * FO + c];
    } else {
        int idx = gid - 3 * FIN * FO;
        if (idx < 3 * FO * FO) {                 // 12288: W2t[m][c][k] = W2[m][k][c]
            int m = idx >> 12, rem = idx & (FO * FO - 1);
            int k = rem >> 6, c = rem & 63;
            const float* src = m == 0 ? W12 : (m == 1 ? W22 : W32);
            W2t[m * FO * FO + c * FO + k] = (f16)src[k * FO + c];
        }
    }
}

// ---------------- kernel 1: q/k/v MLPs (MFMA f16), one m per block ----------
// grid = 3 * 256 blocks (m = bid>>8), block = 256 thr (4 waves x 16 rows)
__global__ __launch_bounds__(256) void k_qkv(
    const float* __restrict__ feat,
    const float* __restrict__ b1q, const float* __restrict__ b2q,
    const float* __restrict__ b1k, const float* __restrict__ b2k,
    const float* __restrict__ b1v, const float* __restrict__ b2v,
    const f16* __restrict__ W1t, const f16* __restrict__ W2t,
    f16* __restrict__ qbuf, f16* __restrict__ kbuf, f16* __restrict__ vtbuf) {
    __shared__ f16 Hs[4][16][68];                // +4 pad
    const int tid = threadIdx.x;
    const int l15 = tid & 15, quad = (tid >> 4) & 3, w = tid >> 6;
    const int m = blockIdx.x >> 8;               // 0=q, 1=k, 2=v
    const int row0 = (blockIdx.x & 255) * 64;    // flat row base (b*N+n)
    const int rbase = row0 + w * 16;
    const int bb = row0 >> 13;                   // batch
    const int n0 = row0 & (NB - 1);

    // X fragments (fp32 -> fp16), 8 k-iters of 16
    f16x4 xf[8];
    const float* xp = feat + (size_t)(rbase + l15) * FIN + quad * 4;
#pragma unroll
    for (int kk = 0; kk < 8; ++kk) {
        float4 t = *(const float4*)(xp + kk * 16);
        f16x4 h; h[0] = (f16)t.x; h[1] = (f16)t.y; h[2] = (f16)t.z; h[3] = (f16)t.w;
        xf[kk] = h;
    }

    const float* b1 = m == 0 ? b1q : (m == 1 ? b1k : b1v);
    const float* b2 = m == 0 ? b2q : (m == 1 ? b2k : b2v);
    const f16* w1 = W1t + m * FIN * FO;
    const f16* w2 = W2t + m * FO * FO;

    f32x4 hacc[4] = {};
#pragma unroll
    for (int kk = 0; kk < 8; ++kk) {
#pragma unroll
        for (int nt = 0; nt < 4; ++nt) {
            f16x4 bf = *(const f16x4*)(w1 + (nt * 16 + l15) * FIN + kk * 16 + quad * 4);
            hacc[nt] = mfma16(xf[kk], bf, hacc[nt]);
        }
    }
#pragma unroll
    for (int nt = 0; nt < 4; ++nt) {
        float bv = b1[nt * 16 + l15];
#pragma unroll
        for (int r = 0; r < 4; ++r) {
            float v = hacc[nt][r] + bv;
            Hs[w][quad * 4 + r][nt * 16 + l15] = (f16)(v > 0.f ? v : 0.f);
        }
    }
    __syncthreads();

    f32x4 oacc[4] = {};
#pragma unroll
    for (int kk = 0; kk < 4; ++kk) {
        f16x4 af = *(const f16x4*)(&Hs[w][l15][kk * 16 + quad * 4]);
#pragma unroll
        for (int nt = 0; nt < 4; ++nt) {
            f16x4 bf = *(const f16x4*)(w2 + (nt * 16 + l15) * FO + kk * 16 + quad * 4);
            oacc[nt] = mfma16(af, bf, oacc[nt]);
        }
    }
#pragma unroll
    for (int nt = 0; nt < 4; ++nt) {
        float bv = b2[nt * 16 + l15];
        int col = nt * 16 + l15;
#pragma unroll
        for (int r = 0; r < 4; ++r) {
            float v = oacc[nt][r] + bv;
            f16 hv = (f16)(v > 0.f ? v : 0.f);
            int rl = w * 16 + quad * 4 + r;
            if (m == 0)      qbuf[(size_t)(row0 + rl) * FO + col] = hv;
            else if (m == 1) kbuf[(size_t)(row0 + rl) * FO + col] = hv;
            else             vtbuf[((size_t)bb * FO + col) * NB + n0 + rl] = hv;
        }
    }
}

// ---------------- kernel 2: flash attention (LDS-staged K/V, transposed-S) --
// grid = B * 128 qblocks * SPLIT = 1024; block = 256 (4 waves x 16 q-rows)
// K/V super-tiles (64x64 f16, 8 KB) staged in double-buffered LDS via
// global_load_lds; XOR-swizzle (16B chunk ^ (row&7)) on BOTH the global source
// and the ds_read side keeps fragment reads at the bank floor.
__global__ __launch_bounds__(256, 4) void k_attn(
    const float* __restrict__ xw,
    const f16* __restrict__ qbuf, const f16* __restrict__ kbuf,
    const f16* __restrict__ vtbuf,
    float* __restrict__ Obuf, float* __restrict__ mbuf, float* __restrict__ lbuf) {
    __shared__ __align__(16) f16 Ks[2][64][64];  // [kv][feat], swizzled
    __shared__ __align__(16) f16 Vs[2][64][64];  // [feat][kv], swizzled

    const int tid = threadIdx.x;
    const int lane = tid & 63;
    const int l15 = tid & 15, quad = (tid >> 4) & 3, w = tid >> 6;
    const int bid = blockIdx.x;
    const int split = bid & (SPLIT - 1);
    const int rest = bid / SPLIT;
    const int qblk = rest & 127;
    const int bb = rest >> 7;
    const int qn = qblk * 64 + w * 16;
    const int kv0 = split * (NB / SPLIT);

    // Q fragments for K=32 MFMA: B-operand = contiguous 8 features per lane
    const f16* qp = qbuf + (size_t)(bb * NB + qn + l15) * FO + quad * 8;
    f16x8 qf[2];
#pragma unroll
    for (int kk = 0; kk < 2; ++kk) qf[kk] = *(const f16x8*)(qp + kk * 32);

    // staging geometry: tile = 64 rows x 8 chunks(16B); wave w owns chunks
    // [(2w)*64 .. (2w+2)*64) of the 512 linear 16B-chunks (2 gload_lds / tile)
    const int cl_a = (w * 2 + 0) * 64 + lane;
    const int cl_b = (w * 2 + 1) * 64 + lane;
    const int row_a = cl_a >> 3, sw_a = (cl_a & 7) ^ (row_a & 7);
    const int row_b = cl_b >> 3, sw_b = (cl_b & 7) ^ (row_b & 7);
    const f16* kb = kbuf + (size_t)(bb * NB + kv0) * FO;
    const f16* vb = vtbuf + (size_t)bb * FO * NB + kv0;

    const float* xwp = xw + (size_t)(bb * NB + qn + l15) * NB + kv0 + quad * 4;

    auto STAGE = [&](int buf, int sp) {
        f16* kd = &Ks[buf][0][0];
        f16* vd = &Vs[buf][0][0];
        GLOAD_LDS16(kb + (size_t)(sp * 64 + row_a) * FO + sw_a * 8, kd + (w * 2 + 0) * 512);
        GLOAD_LDS16(kb + (size_t)(sp * 64 + row_b) * FO + sw_b * 8, kd + (w * 2 + 1) * 512);
        GLOAD_LDS16(vb + (size_t)row_a * NB + sp * 64 + sw_a * 8,   vd + (w * 2 + 0) * 512);
        GLOAD_LDS16(vb + (size_t)row_b * NB + sp * 64 + sw_b * 8,   vd + (w * 2 + 1) * 512);
    };

    f32x4 oacc[4] = {};
    float m_run = 0.f, l_run = 0.f;

    STAGE(0, 0);
    f32x4 xwn[4];
#pragma unroll
    for (int st = 0; st < 4; ++st) xwn[st] = *(const f32x4*)(xwp + st * 16);
    __syncthreads();                             // drains vmcnt -> tile 0 ready

    const int sxor = (l15 & 7) << 4;             // row&7 is l15&7 for all tiles

    for (int sp = 0; sp < NSUP; ++sp) {
        const int cur = sp & 1;
        if (sp + 1 < NSUP) STAGE(cur ^ 1, sp + 1);   // issue next tile early

        f32x4 xwc[4];
#pragma unroll
        for (int st = 0; st < 4; ++st) xwc[st] = xwn[st];
        int spn = (sp + 1 < NSUP) ? sp + 1 : sp;     // prefetch next xw tile
#pragma unroll
        for (int st = 0; st < 4; ++st) xwn[st] = *(const f32x4*)(xwp + spn * 64 + st * 16);

        const char* kbase = (const char*)&Ks[cur][0][0];
        const char* vbase = (const char*)&Vs[cur][0][0];

        // S^T = K_tile @ Q^T via 16x16x32 (A = K rows, 8 contiguous feats/lane)
        f32x4 s[4];
#pragma unroll
        for (int st = 0; st < 4; ++st) {
            f32x4 acc = {};
#pragma unroll
            for (int kk = 0; kk < 2; ++kk) {
                f16x8 kf = *(const f16x8*)(kbase + (st * 16 + l15) * 128 +
                                           ((kk * 64 + quad * 16) ^ sxor));
                acc = mfma32(kf, qf[kk], acc);
            }
            s[st] = acc;
        }
        // scale by xw, relu, tile max
        float tm = 0.f;
#pragma unroll
        for (int st = 0; st < 4; ++st)
#pragma unroll
            for (int r = 0; r < 4; ++r) {
                float v = s[st][r] * xwc[st][r];
                v = v > 0.f ? v : 0.f;
                s[st][r] = v;
                tm = fmaxf(tm, v);
            }
        tm = fmaxf(tm, __shfl_xor(tm, 16));
        tm = fmaxf(tm, __shfl_xor(tm, 32));
        float m_new = fmaxf(m_run, tm);
        float alpha = __expf(m_run - m_new);
        l_run *= alpha;
#pragma unroll
        for (int dt = 0; dt < 4; ++dt)
#pragma unroll
            for (int r = 0; r < 4; ++r) oacc[dt][r] *= alpha;
        m_run = m_new;

        // P^T in C/D layout == B-operand layout for K=16 MFMA
        f16x4 pf[4];
#pragma unroll
        for (int st = 0; st < 4; ++st) {
            float p0 = __expf(s[st][0] - m_new);
            float p1 = __expf(s[st][1] - m_new);
            float p2 = __expf(s[st][2] - m_new);
            float p3 = __expf(s[st][3] - m_new);
            l_run += (p0 + p1) + (p2 + p3);
            f16x4 h; h[0] = (f16)p0; h[1] = (f16)p1; h[2] = (f16)p2; h[3] = (f16)p3;
            pf[st] = h;
        }
        // O^T += V^T @ P^T  (V fragments from swizzled LDS)
#pragma unroll
        for (int st = 0; st < 4; ++st)
#pragma unroll
            for (int dt = 0; dt < 4; ++dt) {
                f16x4 vf = *(const f16x4*)(vbase + (dt * 16 + l15) * 128 +
                                           ((st * 32 + quad * 8) ^ sxor));
                oacc[dt] = mfma16(vf, pf[st], oacc[dt]);
            }

        __syncthreads();   // drains staging (vmcnt 0) + protects buffer reuse
    }

    l_run += __shfl_xor(l_run, 16);
    l_run += __shfl_xor(l_run, 32);

    size_t orow = ((size_t)split * BATCH + bb) * NB + qn + l15;
#pragma unroll
    for (int dt = 0; dt < 4; ++dt)
        *(f32x4*)(Obuf + orow * FO + dt * 16 + quad * 4) = oacc[dt];
    if (quad == 0) { mbuf[orow] = m_run; lbuf[orow] = l_run; }
}

// ---------------- kernel 3: combine splits + final relu ---------------------
__global__ void k_comb(const float* __restrict__ Obuf, const float* __restrict__ mbuf,
                       const float* __restrict__ lbuf, float* __restrict__ out) {
    int gid = blockIdx.x * 256 + threadIdx.x;    // < 1048576
    int bn = gid >> 6;
    const int S = BATCH * NB;                    // 16384
    float m0 = mbuf[bn], m1 = mbuf[S + bn], m2 = mbuf[2 * S + bn], m3 = mbuf[3 * S + bn];
    float M = fmaxf(fmaxf(m0, m1), fmaxf(m2, m3));
    float e0 = __expf(m0 - M), e1 = __expf(m1 - M), e2 = __expf(m2 - M), e3 = __expf(m3 - M);
    float L = lbuf[bn] * e0 + lbuf[S + bn] * e1 + lbuf[2 * S + bn] * e2 + lbuf[3 * S + bn] * e3;
    const int ST = S * FO;                       // 1048576
    float o = Obuf[gid] * e0 + Obuf[gid + ST] * e1 + Obuf[gid + 2 * ST] * e2 + Obuf[gid + 3 * ST] * e3;
    float v = o / L;
    out[gid] = v > 0.f ? v : 0.f;
}

// ---------------------------------------------------------------------------
extern "C" void kernel_launch(void* const* d_in, const int* in_sizes, int n_in,
                              void* d_out, int out_size, void* d_ws, size_t ws_size,
                              hipStream_t stream) {
    const float* feat = (const float*)d_in[0];
    const float* xw   = (const float*)d_in[1];
    const float* W11 = (const float*)d_in[2];  const float* b11 = (const float*)d_in[3];
    const float* W12 = (const float*)d_in[4];  const float* b12 = (const float*)d_in[5];
    const float* W21 = (const float*)d_in[6];  const float* b21 = (const float*)d_in[7];
    const float* W22 = (const float*)d_in[8];  const float* b22 = (const float*)d_in[9];
    const float* W31 = (const float*)d_in[10]; const float* b31 = (const float*)d_in[11];
    const float* W32 = (const float*)d_in[12]; const float* b32 = (const float*)d_in[13];

    char* ws = (char*)d_ws;
    f16*   W1t  = (f16*)(ws);                        // 49152 B
    f16*   W2t  = (f16*)(ws + 49152);                // 24576 B
    f16*   qbuf = (f16*)(ws + 73728);                // 2 MB
    f16*   kbuf = (f16*)(ws + 73728 + 2097152);      // 2 MB
    f16*   vtbuf= (f16*)(ws + 73728 + 4194304);      // 2 MB
    float* Obuf = (float*)(ws + 73728 + 6291456);    // 16 MB
    float* mbuf = (float*)(ws + 73728 + 23068672);   // 256 KB
    float* lbuf = (float*)(ws + 73728 + 23330816);   // 256 KB

    k_prep<<<144, 256, 0, stream>>>(W11, W21, W31, W12, W22, W32, W1t, W2t);
    k_qkv<<<768, 256, 0, stream>>>(feat, b11, b12, b21, b22, b31, b32,
                                   W1t, W2t, qbuf, kbuf, vtbuf);
    k_attn<<<BATCH * 128 * SPLIT, 256, 0, stream>>>(xw, qbuf, kbuf, vtbuf,
                                                    Obuf, mbuf, lbuf);
    k_comb<<<4096, 256, 0, stream>>>(Obuf, mbuf, lbuf, (float*)d_out);
}

// Round 2
// 763.697 us; speedup vs baseline: 1.4324x; 1.0073x over previous
//
#include <hip/hip_runtime.h>

#define NB   8192
#define BATCH 2
#define FIN  128
#define FO   64
#define SPLIT 4
#define NSUP (NB / SPLIT / 64)                  // 32 super-tiles of 64 kv

typedef _Float16 f16;
typedef _Float16 f16x4 __attribute__((ext_vector_type(4)));
typedef _Float16 f16x8 __attribute__((ext_vector_type(8)));
typedef float    f32x4 __attribute__((ext_vector_type(4)));

__device__ __forceinline__ f32x4 mfma16(f16x4 a, f16x4 b, f32x4 c) {
    return __builtin_amdgcn_mfma_f32_16x16x16f16(a, b, c, 0, 0, 0);
}
__device__ __forceinline__ f32x4 mfma32(f16x8 a, f16x8 b, f32x4 c) {
    return __builtin_amdgcn_mfma_f32_16x16x32_f16(a, b, c, 0, 0, 0);
}

#define GLOAD_LDS16(gsrc, ldst)                                                   \
    __builtin_amdgcn_global_load_lds(                                             \
        (const __attribute__((address_space(1))) unsigned int*)(gsrc),            \
        (__attribute__((address_space(3))) unsigned int*)(ldst), 16, 0, 0)

// ---------------- kernel 0: weight prep (fp32 -> fp16, transposed) ----------
__global__ void k_prep(const float* __restrict__ W11, const float* __restrict__ W21,
                       const float* __restrict__ W31, const float* __restrict__ W12,
                       const float* __restrict__ W22, const float* __restrict__ W32,
                       f16* __restrict__ W1t, f16* __restrict__ W2t) {
    int gid = blockIdx.x * 256 + threadIdx.x;
    if (gid < 3 * FIN * FO) {                    // 24576: W1t[m][c][k] = W1[m][k][c]
        int m = gid >> 13, rem = gid & (FIN * FO - 1);
        int k = rem >> 6, c = rem & 63;
        const float* src = m == 0 ? W11 : (m == 1 ? W21 : W31);
        W1t[m * FIN * FO + c * FIN + k] = (f16)src[k * FO + c];
    } else {
        int idx = gid - 3 * FIN * FO;
        if (idx < 3 * FO * FO) {                 // 12288: W2t[m][c][k] = W2[m][k][c]
            int m = idx >> 12, rem = idx & (FO * FO - 1);
            int k = rem >> 6, c = rem & 63;
            const float* src = m == 0 ? W12 : (m == 1 ? W22 : W32);
            W2t[m * FO * FO + c * FO + k] = (f16)src[k * FO + c];
        }
    }
}

// ---------------- kernel 1: q/k/v MLPs (MFMA f16), one m per block ----------
// grid = 3 * 256 blocks (m = bid>>8), block = 256 thr (4 waves x 16 rows)
// V output transposed through LDS so vtbuf writes are 32B-contiguous/thread.
__global__ __launch_bounds__(256) void k_qkv(
    const float* __restrict__ feat,
    const float* __restrict__ b1q, const float* __restrict__ b2q,
    const float* __restrict__ b1k, const float* __restrict__ b2k,
    const float* __restrict__ b1v, const float* __restrict__ b2v,
    const f16* __restrict__ W1t, const f16* __restrict__ W2t,
    f16* __restrict__ qbuf, f16* __restrict__ kbuf, f16* __restrict__ vtbuf) {
    __shared__ f16 Hs[4][16][68];                // +4 pad
    __shared__ f16 Vt[64][72];                   // [c][n], +8 pad
    const int tid = threadIdx.x;
    const int l15 = tid & 15, quad = (tid >> 4) & 3, w = tid >> 6;
    const int m = blockIdx.x >> 8;               // 0=q, 1=k, 2=v
    const int row0 = (blockIdx.x & 255) * 64;    // flat row base (b*N+n)
    const int rbase = row0 + w * 16;
    const int bb = row0 >> 13;                   // batch
    const int n0 = row0 & (NB - 1);

    // X fragments (fp32 -> fp16), 8 k-iters of 16
    f16x4 xf[8];
    const float* xp = feat + (size_t)(rbase + l15) * FIN + quad * 4;
#pragma unroll
    for (int kk = 0; kk < 8; ++kk) {
        float4 t = *(const float4*)(xp + kk * 16);
        f16x4 h; h[0] = (f16)t.x; h[1] = (f16)t.y; h[2] = (f16)t.z; h[3] = (f16)t.w;
        xf[kk] = h;
    }

    const float* b1 = m == 0 ? b1q : (m == 1 ? b1k : b1v);
    const float* b2 = m == 0 ? b2q : (m == 1 ? b2k : b2v);
    const f16* w1 = W1t + m * FIN * FO;
    const f16* w2 = W2t + m * FO * FO;

    f32x4 hacc[4] = {};
#pragma unroll
    for (int kk = 0; kk < 8; ++kk) {
#pragma unroll
        for (int nt = 0; nt < 4; ++nt) {
            f16x4 bf = *(const f16x4*)(w1 + (nt * 16 + l15) * FIN + kk * 16 + quad * 4);
            hacc[nt] = mfma16(xf[kk], bf, hacc[nt]);
        }
    }
#pragma unroll
    for (int nt = 0; nt < 4; ++nt) {
        float bv = b1[nt * 16 + l15];
#pragma unroll
        for (int r = 0; r < 4; ++r) {
            float v = hacc[nt][r] + bv;
            Hs[w][quad * 4 + r][nt * 16 + l15] = (f16)(v > 0.f ? v : 0.f);
        }
    }
    __syncthreads();

    f32x4 oacc[4] = {};
#pragma unroll
    for (int kk = 0; kk < 4; ++kk) {
        f16x4 af = *(const f16x4*)(&Hs[w][l15][kk * 16 + quad * 4]);
#pragma unroll
        for (int nt = 0; nt < 4; ++nt) {
            f16x4 bf = *(const f16x4*)(w2 + (nt * 16 + l15) * FO + kk * 16 + quad * 4);
            oacc[nt] = mfma16(af, bf, oacc[nt]);
        }
    }
    if (m == 2) {
        // transpose V tile through LDS: Vt[c][n], then coalesced global stores
#pragma unroll
        for (int nt = 0; nt < 4; ++nt) {
            float bv = b2[nt * 16 + l15];
            f16x4 h;
#pragma unroll
            for (int r = 0; r < 4; ++r) {
                float v = oacc[nt][r] + bv;
                h[r] = (f16)(v > 0.f ? v : 0.f);
            }
            *(f16x4*)&Vt[nt * 16 + l15][w * 16 + quad * 4] = h;
        }
        __syncthreads();
        int c = tid >> 2, part = tid & 3;
        f16x8 v0 = *(const f16x8*)&Vt[c][part * 16];
        f16x8 v1 = *(const f16x8*)&Vt[c][part * 16 + 8];
        f16* dst = vtbuf + ((size_t)bb * FO + c) * NB + n0 + part * 16;
        *(f16x8*)dst = v0;
        *(f16x8*)(dst + 8) = v1;
    } else {
#pragma unroll
        for (int nt = 0; nt < 4; ++nt) {
            float bv = b2[nt * 16 + l15];
            int col = nt * 16 + l15;
#pragma unroll
            for (int r = 0; r < 4; ++r) {
                float v = oacc[nt][r] + bv;
                f16 hv = (f16)(v > 0.f ? v : 0.f);
                int rl = w * 16 + quad * 4 + r;
                if (m == 0) qbuf[(size_t)(row0 + rl) * FO + col] = hv;
                else        kbuf[(size_t)(row0 + rl) * FO + col] = hv;
            }
        }
    }
}

// ---------------- kernel 2: flash attention (LDS-staged K/V, counted vmcnt) -
// grid = B * 128 qblocks * SPLIT = 1024; block = 256 (4 waves x 16 q-rows)
// Double-buffered K/V staging via global_load_lds + XOR swizzle (both sides).
// Raw s_barrier with counted vmcnt(4): the 4 xw prefetch loads stay in flight
// across the barrier (T3/T4); xw prefetched 2 tiles deep, unroll-by-2 so the
// prefetch target alternates registers with no rotation movs.
__global__ __launch_bounds__(256, 4) void k_attn(
    const float* __restrict__ xw,
    const f16* __restrict__ qbuf, const f16* __restrict__ kbuf,
    const f16* __restrict__ vtbuf,
    float* __restrict__ Obuf, float* __restrict__ mbuf, float* __restrict__ lbuf) {
    __shared__ __align__(16) f16 Ks[2][64][64];  // [kv][feat], swizzled
    __shared__ __align__(16) f16 Vs[2][64][64];  // [feat][kv], swizzled

    const int tid = threadIdx.x;
    const int lane = tid & 63;
    const int l15 = tid & 15, quad = (tid >> 4) & 3, w = tid >> 6;
    const int bid = blockIdx.x;
    const int split = bid & (SPLIT - 1);
    const int rest = bid / SPLIT;
    const int qblk = rest & 127;
    const int bb = rest >> 7;
    const int qn = qblk * 64 + w * 16;
    const int kv0 = split * (NB / SPLIT);

    // Q fragments for K=32 MFMA: B-operand = contiguous 8 features per lane
    const f16* qp = qbuf + (size_t)(bb * NB + qn + l15) * FO + quad * 8;
    f16x8 qf[2];
#pragma unroll
    for (int kk = 0; kk < 2; ++kk) qf[kk] = *(const f16x8*)(qp + kk * 32);

    // staging geometry: tile = 64 rows x 8 chunks(16B); wave w owns chunks
    // [(2w)*64 .. (2w+2)*64) of the 512 linear 16B-chunks
    const int cl_a = (w * 2 + 0) * 64 + lane;
    const int cl_b = (w * 2 + 1) * 64 + lane;
    const int row_a = cl_a >> 3, sw_a = (cl_a & 7) ^ (row_a & 7);
    const int row_b = cl_b >> 3, sw_b = (cl_b & 7) ^ (row_b & 7);
    const f16* kb = kbuf + (size_t)(bb * NB + kv0) * FO;
    const f16* vb = vtbuf + (size_t)bb * FO * NB + kv0;

    const float* xwp = xw + (size_t)(bb * NB + qn + l15) * NB + kv0 + quad * 4;

    auto STAGE = [&](int buf, int sp) {
        f16* kd = &Ks[buf][0][0];
        f16* vd = &Vs[buf][0][0];
        GLOAD_LDS16(kb + (size_t)(sp * 64 + row_a) * FO + sw_a * 8, kd + (w * 2 + 0) * 512);
        GLOAD_LDS16(kb + (size_t)(sp * 64 + row_b) * FO + sw_b * 8, kd + (w * 2 + 1) * 512);
        GLOAD_LDS16(vb + (size_t)row_a * NB + sp * 64 + sw_a * 8,   vd + (w * 2 + 0) * 512);
        GLOAD_LDS16(vb + (size_t)row_b * NB + sp * 64 + sw_b * 8,   vd + (w * 2 + 1) * 512);
    };

    f32x4 oacc[4] = {};
    float m_run = 0.f, l_run = 0.f;
    const int sxor = (l15 & 7) << 4;             // row&7 is l15&7 for all tiles

    f32x4 xwA[4], xwB[4];
    STAGE(0, 0);
#pragma unroll
    for (int st = 0; st < 4; ++st) {
        xwA[st] = *(const f32x4*)(xwp + st * 16);
        xwB[st] = *(const f32x4*)(xwp + 64 + st * 16);
    }
    asm volatile("s_waitcnt vmcnt(0)" ::: "memory");   // tile 0 staged
    __builtin_amdgcn_s_barrier();
    __builtin_amdgcn_sched_barrier(0);

    auto ITER = [&](int sp, f32x4 (&xwc)[4]) {
        const int cur = sp & 1;
        if (sp + 1 < NSUP) STAGE(cur ^ 1, sp + 1);   // oldest VMEM this iter

        const char* kbase = (const char*)&Ks[cur][0][0];
        const char* vbase = (const char*)&Vs[cur][0][0];

        // S^T = K_tile @ Q^T via 16x16x32
        f32x4 s[4];
        __builtin_amdgcn_s_setprio(1);
#pragma unroll
        for (int st = 0; st < 4; ++st) {
            f32x4 acc = {};
#pragma unroll
            for (int kk = 0; kk < 2; ++kk) {
                f16x8 kf = *(const f16x8*)(kbase + (st * 16 + l15) * 128 +
                                           ((kk * 64 + quad * 16) ^ sxor));
                acc = mfma32(kf, qf[kk], acc);
            }
            s[st] = acc;
        }
        __builtin_amdgcn_s_setprio(0);

        // scale by xw, relu, tile max
        float tm = 0.f;
#pragma unroll
        for (int st = 0; st < 4; ++st)
#pragma unroll
            for (int r = 0; r < 4; ++r) {
                float v = s[st][r] * xwc[st][r];
                v = v > 0.f ? v : 0.f;
                s[st][r] = v;
                tm = fmaxf(tm, v);
            }
        tm = fmaxf(tm, __shfl_xor(tm, 16));
        tm = fmaxf(tm, __shfl_xor(tm, 32));
        float m_new = fmaxf(m_run, tm);
        float alpha = __expf(m_run - m_new);
        l_run *= alpha;
#pragma unroll
        for (int dt = 0; dt < 4; ++dt)
#pragma unroll
            for (int r = 0; r < 4; ++r) oacc[dt][r] *= alpha;
        m_run = m_new;

        // P^T in C/D layout == B-operand layout for K=16 MFMA
        f16x4 pf[4];
#pragma unroll
        for (int st = 0; st < 4; ++st) {
            float p0 = __expf(s[st][0] - m_new);
            float p1 = __expf(s[st][1] - m_new);
            float p2 = __expf(s[st][2] - m_new);
            float p3 = __expf(s[st][3] - m_new);
            l_run += (p0 + p1) + (p2 + p3);
            f16x4 h; h[0] = (f16)p0; h[1] = (f16)p1; h[2] = (f16)p2; h[3] = (f16)p3;
            pf[st] = h;
        }
        // O^T += V^T @ P^T
        __builtin_amdgcn_s_setprio(1);
#pragma unroll
        for (int st = 0; st < 4; ++st)
#pragma unroll
            for (int dt = 0; dt < 4; ++dt) {
                f16x4 vf = *(const f16x4*)(vbase + (dt * 16 + l15) * 128 +
                                           ((st * 32 + quad * 8) ^ sxor));
                oacc[dt] = mfma16(vf, pf[st], oacc[dt]);
            }
        __builtin_amdgcn_s_setprio(0);

        // xw prefetch 2 tiles ahead, AFTER xwc consumed; the memory-clobber
        // asm pins issue order: [stage x4 (oldest)] ... [xw x4 (newest)]
        asm volatile("" ::: "memory");
        if (sp + 2 < NSUP) {
#pragma unroll
            for (int st = 0; st < 4; ++st)
                xwc[st] = *(const f32x4*)(xwp + (sp + 2) * 64 + st * 16);
            asm volatile("s_waitcnt vmcnt(4)" ::: "memory");  // staging done, xw in flight
        } else if (sp + 1 < NSUP) {
            asm volatile("s_waitcnt vmcnt(0)" ::: "memory");  // tail: drain staging
        }
        if (sp + 1 < NSUP) {
            __builtin_amdgcn_s_barrier();
            __builtin_amdgcn_sched_barrier(0);
        }
    };

    for (int sp = 0; sp < NSUP; sp += 2) {
        ITER(sp, xwA);
        ITER(sp + 1, xwB);
    }

    l_run += __shfl_xor(l_run, 16);
    l_run += __shfl_xor(l_run, 32);

    size_t orow = ((size_t)split * BATCH + bb) * NB + qn + l15;
#pragma unroll
    for (int dt = 0; dt < 4; ++dt)
        *(f32x4*)(Obuf + orow * FO + dt * 16 + quad * 4) = oacc[dt];
    if (quad == 0) { mbuf[orow] = m_run; lbuf[orow] = l_run; }
}

// ---------------- kernel 3: combine splits + final relu ---------------------
__global__ void k_comb(const float* __restrict__ Obuf, const float* __restrict__ mbuf,
                       const float* __restrict__ lbuf, float* __restrict__ out) {
    int gid = blockIdx.x * 256 + threadIdx.x;    // < 1048576
    int bn = gid >> 6;
    const int S = BATCH * NB;                    // 16384
    float m0 = mbuf[bn], m1 = mbuf[S + bn], m2 = mbuf[2 * S + bn], m3 = mbuf[3 * S + bn];
    float M = fmaxf(fmaxf(m0, m1), fmaxf(m2, m3));
    float e0 = __expf(m0 - M), e1 = __expf(m1 - M), e2 = __expf(m2 - M), e3 = __expf(m3 - M);
    float L = lbuf[bn] * e0 + lbuf[S + bn] * e1 + lbuf[2 * S + bn] * e2 + lbuf[3 * S + bn] * e3;
    const int ST = S * FO;                       // 1048576
    float o = Obuf[gid] * e0 + Obuf[gid + ST] * e1 + Obuf[gid + 2 * ST] * e2 + Obuf[gid + 3 * ST] * e3;
    float v = o / L;
    out[gid] = v > 0.f ? v : 0.f;
}

// ---------------------------------------------------------------------------
extern "C" void kernel_launch(void* const* d_in, const int* in_sizes, int n_in,
                              void* d_out, int out_size, void* d_ws, size_t ws_size,
                              hipStream_t stream) {
    const float* feat = (const float*)d_in[0];
    const float* xw   = (const float*)d_in[1];
    const float* W11 = (const float*)d_in[2];  const float* b11 = (const float*)d_in[3];
    const float* W12 = (const float*)d_in[4];  const float* b12 = (const float*)d_in[5];
    const float* W21 = (const float*)d_in[6];  const float* b21 = (const float*)d_in[7];
    const float* W22 = (const float*)d_in[8];  const float* b22 = (const float*)d_in[9];
    const float* W31 = (const float*)d_in[10]; const float* b31 = (const float*)d_in[11];
    const float* W32 = (const float*)d_in[12]; const float* b32 = (const float*)d_in[13];

    char* ws = (char*)d_ws;
    f16*   W1t  = (f16*)(ws);                        // 49152 B
    f16*   W2t  = (f16*)(ws + 49152);                // 24576 B
    f16*   qbuf = (f16*)(ws + 73728);                // 2 MB
    f16*   kbuf = (f16*)(ws + 73728 + 2097152);      // 2 MB
    f16*   vtbuf= (f16*)(ws + 73728 + 4194304);      // 2 MB
    float* Obuf = (float*)(ws + 73728 + 6291456);    // 16 MB
    float* mbuf = (float*)(ws + 73728 + 23068672);   // 256 KB
    float* lbuf = (float*)(ws + 73728 + 23330816);   // 256 KB

    k_prep<<<144, 256, 0, stream>>>(W11, W21, W31, W12, W22, W32, W1t, W2t);
    k_qkv<<<768, 256, 0, stream>>>(feat, b11, b12, b21, b22, b31, b32,
                                   W1t, W2t, qbuf, kbuf, vtbuf);
    k_attn<<<BATCH * 128 * SPLIT, 256, 0, stream>>>(xw, qbuf, kbuf, vtbuf,
                                                    Obuf, mbuf, lbuf);
    k_comb<<<4096, 256, 0, stream>>>(Obuf, mbuf, lbuf, (float*)d_out);
}